// Round 13
// baseline (823.081 us; speedup 1.0000x reference)
//
#include <hip/hip_runtime.h>

// ---------------------------------------------------------------------------
// PWAM fused pipeline, bf16 MFMA GEMMs + MFMA attention (swapped-QK, IN folded)
// R13: (1) x f32->bf16 conversion fused into gemm0 via reg-staged A (T14
//      issue-early/write-late split; B stays global_load_lds); standalone cvt
//      now weights-only. (2) GEMM LDS trimmed to exactly 32KB (stats partials
//      written per-wave-half, no red[] array) -> 5 blocks/CU.
// B=16, HW=3600, D=KC=VC=512, LC=768, NL=20, H=8
// ---------------------------------------------------------------------------

#define B_   16
#define HW_  3600
#define D_   512
#define LC_  768
#define NL_  20

typedef __attribute__((ext_vector_type(8))) __bf16 bf16x8;
typedef __attribute__((ext_vector_type(4))) float f32x4;
typedef __attribute__((ext_vector_type(4))) float float4v;
typedef __attribute__((ext_vector_type(8))) unsigned short ushort8v;
typedef __attribute__((ext_vector_type(4))) unsigned short ushort4v;
typedef __attribute__((ext_vector_type(2))) unsigned int uint2v;

static __device__ __forceinline__ float bf2f(unsigned short u){
  unsigned int x = ((unsigned int)u) << 16; float f;
  __builtin_memcpy(&f, &x, 4); return f;
}
static __device__ __forceinline__ unsigned short f2bf(float f){
  __bf16 h = (__bf16)f;
  unsigned short u; __builtin_memcpy(&u, &h, 2); return u;
}
static __device__ __forceinline__ unsigned int pack2bf(float lo, float hi){
  return (unsigned int)f2bf(lo) | ((unsigned int)f2bf(hi) << 16);
}
// gelu(x) = 0.5x(1+erf(x/sqrt2)); erf via A&S 7.1.26 (|err|<=1.5e-7), hw exp.
static __device__ __forceinline__ float gelu_f(float x){
  float z  = x * 0.7071067811865476f;
  float az = fabsf(z);
  float t = 1.0f / fmaf(0.3275911f, az, 1.0f);
  float p = fmaf(1.061405429f, t, -1.453152027f);
  p = fmaf(p, t, 1.421413741f);
  p = fmaf(p, t, -0.284496736f);
  p = fmaf(p, t, 0.254829592f);
  p = p * t;
  float er = 1.0f - p * __expf(-az * az);
  er = copysignf(er, z);
  return 0.5f * x * (1.0f + er);
}

// --------------------------- weights f32 -> bf16 ----------------------------
__global__ void k_cvt_w(const float* __restrict__ Wvis, const float* __restrict__ Wq,
                        const float* __restrict__ Ww,   const float* __restrict__ Wmm,
                        unsigned short* __restrict__ wcat,
                        unsigned short* __restrict__ wwb, unsigned short* __restrict__ wmmb){
  const int TOT = 4 * 65536;
  int i = blockIdx.x * 256 + threadIdx.x;
  int stride = gridDim.x * 256;
  for (; i < TOT; i += stride){
    int seg = i >> 16, o = i & 0xFFFF;
    const float4v* s; ushort4v* dp;
    if      (seg == 0){ s = (const float4v*)Wvis + o; dp = (ushort4v*)wcat + o; }
    else if (seg == 1){ s = (const float4v*)Wq   + o; dp = (ushort4v*)wcat + 65536 + o; }
    else if (seg == 2){ s = (const float4v*)Ww   + o; dp = (ushort4v*)wwb + o; }
    else              { s = (const float4v*)Wmm  + o; dp = (ushort4v*)wmmb + o; }
    float4v v = *s;
    ushort4v u;
    u.x = f2bf(v.x); u.y = f2bf(v.y); u.z = f2bf(v.z); u.w = f2bf(v.w);
    *dp = u;
  }
}

// --------------------------- K/V projections (tiny) -------------------------
__global__ void k_kv(const float* __restrict__ l, const float* __restrict__ l_mask,
                     const float* __restrict__ Wk, const float* __restrict__ bk,
                     const float* __restrict__ Wval, const float* __restrict__ bval,
                     float* __restrict__ k_s, float* __restrict__ v_s){
  const int b = blockIdx.y;
  const int part = blockIdx.x;
  const bool isK = part < 8;
  const int c0 = (part & 7) * 64;
  const float* W  = isK ? Wk : Wval;
  const float* bi = isK ? bk : bval;
  float* outp = isK ? k_s : v_s;

  __shared__ float l_sh[LC_ * NL_];
  for (int i = threadIdx.x; i < LC_ * NL_; i += 256)
    l_sh[i] = l[(size_t)b * LC_ * NL_ + i];
  __syncthreads();

  const int tid = threadIdx.x;
  const int cl = tid >> 2;
  const int q  = tid & 3;
  const int c  = c0 + cl;
  const float* wrow = W + (size_t)c * LC_;
  float acc[5] = {0.f,0.f,0.f,0.f,0.f};
  for (int i = 0; i < LC_; ++i){
    float wv = wrow[i];
    const float* lr = l_sh + i * NL_ + q * 5;
    acc[0] = fmaf(wv, lr[0], acc[0]);
    acc[1] = fmaf(wv, lr[1], acc[1]);
    acc[2] = fmaf(wv, lr[2], acc[2]);
    acc[3] = fmaf(wv, lr[3], acc[3]);
    acc[4] = fmaf(wv, lr[4], acc[4]);
  }
  const float bb = bi[c];
  #pragma unroll
  for (int n5 = 0; n5 < 5; ++n5){
    int n = q * 5 + n5;
    float m = l_mask[b * NL_ + n];
    float val = (acc[n5] + bb) * m;
    if (isK) val *= 0.04419417382415922f;   // 1/sqrt(512) folded into K
    outp[((size_t)b * 512 + c) * NL_ + n] = val;
  }
}

// --------------------------- GEMM (bf16 MFMA, 128x128 tile) -----------------
// 2-buffer LDS = exactly 32KB -> 5 blocks/CU. vmcnt(0)+lgkm drain before raw
// s_barrier (R6 discipline). XOR bank swizzle (key (row>>1)&3) both sides.
// AF32: A streamed from f32 global via regs (issue-early/cvt+ds_write-late).
// Stats partials: per (wr) half -> partial[...*1024 + wr*512 + col].
// MODE 0: dual out (NT=8): n<512 -> o0=bf16(v) RAW; else o1=bf16(v)
// MODE 1: o0 = bf16(v);  MODE 2: of = gelu(v) f32
template<int MODE, int NT, bool STATS, bool AF32>
__global__ __launch_bounds__(256, 5) void k_gemm(
    const unsigned short* __restrict__ A,
    const float* __restrict__ Afp,
    const unsigned short* __restrict__ Bm,
    const float* __restrict__ bias0, const float* __restrict__ bias1,
    unsigned short* __restrict__ o0, unsigned short* __restrict__ o1,
    float* __restrict__ of, float2* __restrict__ partial)
{
  __shared__ __align__(16) unsigned short smem[2][2][128 * 32];  // exactly 32 KB

  const int nwg = 29 * NT * B_;
  const int per = nwg >> 3;
  const int d = blockIdx.x;
  const int g = (d & 7) * per + (d >> 3);
  constexpr int NSH = (NT == 8) ? 3 : 2;
  const int nt = g & (NT - 1);
  const int rem = g >> NSH;
  const int mt = rem % 29;
  const int b  = rem / 29;

  const int m0 = mt * 128;
  const int n0 = nt * 128;
  const int tid = threadIdx.x;
  const int w = tid >> 6, lane = tid & 63;
  const int wr = w >> 1, wc = w & 1;
  const int lr_ = lane & 15, lg_ = lane >> 4;
  const int mvalid = HW_ - m0;
  const unsigned short* Ab = A + (size_t)b * HW_ * 512;
  const float* Afb = Afp + (size_t)b * HW_ * 512;

  f32x4 acc[4][4];
  #pragma unroll
  for (int i = 0; i < 4; ++i)
    #pragma unroll
    for (int j = 0; j < 4; ++j)
      acc[i][j] = (f32x4){0.f, 0.f, 0.f, 0.f};

  // ---- A staging (bf16 gload_lds path) ----
  auto stageA = [&](int kt, int buf){
    const int k0 = kt * 32;
    #pragma unroll
    for (int s = 0; s < 2; ++s){
      int chunk = s * 256 + tid;
      int row = chunk >> 2, part = chunk & 3;
      int psrc = part ^ ((row >> 1) & 3);
      int grow = row < mvalid ? row : (mvalid - 1);
      const unsigned short* gsrc = Ab + ((size_t)(m0 + grow) * 512 + k0 + psrc * 8);
      unsigned short* ldst = &smem[0][buf][(s * 256 + w * 64) * 8];
      __builtin_amdgcn_global_load_lds((const __attribute__((address_space(1))) void*)gsrc,
                                       (__attribute__((address_space(3))) void*)ldst, 16, 0, 0);
    }
  };
  // ---- A staging (f32 reg path): issue loads ----
  float4v Ar[2][2];
  auto issueA = [&](int kt){
    const int k0 = kt * 32;
    #pragma unroll
    for (int s = 0; s < 2; ++s){
      int chunk = s * 256 + tid;
      int row = chunk >> 2, part = chunk & 3;
      int psrc = part ^ ((row >> 1) & 3);
      int grow = row < mvalid ? row : (mvalid - 1);
      const float* gs = Afb + ((size_t)(m0 + grow) * 512 + k0 + psrc * 8);
      Ar[s][0] = *(const float4v*)(gs);
      Ar[s][1] = *(const float4v*)(gs + 4);
    }
  };
  // ---- cvt + ds_write (same linear layout as gload_lds dest) ----
  auto writeA = [&](int buf){
    #pragma unroll
    for (int s = 0; s < 2; ++s){
      ushort8v o;
      o[0] = f2bf(Ar[s][0].x); o[1] = f2bf(Ar[s][0].y);
      o[2] = f2bf(Ar[s][0].z); o[3] = f2bf(Ar[s][0].w);
      o[4] = f2bf(Ar[s][1].x); o[5] = f2bf(Ar[s][1].y);
      o[6] = f2bf(Ar[s][1].z); o[7] = f2bf(Ar[s][1].w);
      *(ushort8v*)(&smem[0][buf][(s * 256 + tid) * 8]) = o;
    }
  };
  auto stageB = [&](int kt, int buf){
    const int k0 = kt * 32;
    #pragma unroll
    for (int s = 0; s < 2; ++s){
      int chunk = s * 256 + tid;
      int row = chunk >> 2, part = chunk & 3;
      int psrc = part ^ ((row >> 1) & 3);
      const unsigned short* gsrc = Bm + ((size_t)(n0 + row) * 512 + k0 + psrc * 8);
      unsigned short* ldst = &smem[1][buf][(s * 256 + w * 64) * 8];
      __builtin_amdgcn_global_load_lds((const __attribute__((address_space(1))) void*)gsrc,
                                       (__attribute__((address_space(3))) void*)ldst, 16, 0, 0);
    }
  };

  auto compute = [&](int buf){
    const unsigned short* lA = &smem[0][buf][(wr * 64) * 32];
    const unsigned short* lB = &smem[1][buf][(wc * 64) * 32];
    const int kx = (lg_ ^ ((lr_ >> 1) & 3)) * 8;
    bf16x8 av[4], bv[4];
    #pragma unroll
    for (int i = 0; i < 4; ++i) av[i] = *(const bf16x8*)(lA + (i * 16 + lr_) * 32 + kx);
    #pragma unroll
    for (int j = 0; j < 4; ++j) bv[j] = *(const bf16x8*)(lB + (j * 16 + lr_) * 32 + kx);
    #pragma unroll
    for (int i = 0; i < 4; ++i)
      #pragma unroll
      for (int j = 0; j < 4; ++j)
        acc[i][j] = __builtin_amdgcn_mfma_f32_16x16x32_bf16(av[i], bv[j], acc[i][j], 0, 0, 0);
  };

  // prologue: tile 0
  if (AF32){
    issueA(0);
    stageB(0, 0);
    writeA(0);            // compiler inserts vmcnt for Ar deps
  } else {
    stageA(0, 0);
    stageB(0, 0);
  }

  #pragma unroll
  for (int t = 0; t < 16; ++t){
    // R6-proven discipline: drain own LDS ops + all VMEM before the barrier.
    asm volatile("s_waitcnt lgkmcnt(0)" ::: "memory");
    __builtin_amdgcn_sched_barrier(0);
    asm volatile("s_waitcnt vmcnt(0)" ::: "memory");
    __builtin_amdgcn_s_barrier();
    __builtin_amdgcn_sched_barrier(0);
    const int nb = (t + 1) & 1;
    if (t < 15){
      if (AF32) issueA(t + 1);
      else      stageA(t + 1, nb);
      stageB(t + 1, nb);
      if (AF32) __builtin_amdgcn_sched_barrier(0);   // pin load issue before MFMAs
    }
    compute(t & 1);
    if (AF32 && t < 15) writeA(nb);   // vmcnt waits auto-inserted for Ar
  }

  // ---- epilogue ----
  const int colbase = n0 + wc * 64;
  float bsv[4];
  #pragma unroll
  for (int j = 0; j < 4; ++j){
    int col = colbase + j * 16 + lr_;
    if (MODE == 0) bsv[j] = (col < 512) ? bias0[col] : bias1[col - 512];
    else           bsv[j] = bias0[col];
  }
  const bool do_stats = STATS && (MODE != 0 || n0 >= 512);

  if (STATS && do_stats){
    float colsum[4] = {0.f,0.f,0.f,0.f}, colsq[4] = {0.f,0.f,0.f,0.f};
    #pragma unroll
    for (int i = 0; i < 4; ++i){
      int rowb = m0 + wr * 64 + i * 16 + lg_ * 4;
      #pragma unroll
      for (int rr = 0; rr < 4; ++rr){
        if (rowb + rr < HW_){
          #pragma unroll
          for (int j = 0; j < 4; ++j){
            float v = acc[i][j][rr] + bsv[j];
            colsum[j] += v;
            colsq[j]  = fmaf(v, v, colsq[j]);
          }
        }
      }
    }
    #pragma unroll
    for (int j = 0; j < 4; ++j){
      colsum[j] += __shfl_xor(colsum[j], 16);
      colsum[j] += __shfl_xor(colsum[j], 32);
      colsq[j]  += __shfl_xor(colsq[j], 16);
      colsq[j]  += __shfl_xor(colsq[j], 32);
    }
    if (lg_ == 0){
      #pragma unroll
      for (int j = 0; j < 4; ++j){
        int gcol = colbase + j * 16 + lr_ - (MODE == 0 ? 512 : 0);
        partial[((size_t)b * 29 + mt) * 1024 + wr * 512 + gcol] =
          make_float2(colsum[j], colsq[j]);
      }
    }
  }

  __syncthreads();   // K-loop LDS reads done -> smem reusable for C staging

  unsigned short* stw = &smem[0][0][0] + w * 4096;   // 8KB wave-private

  if (MODE == 2){
    float* stgf = (float*)stw;
    #pragma unroll
    for (int half = 0; half < 2; ++half){
      #pragma unroll
      for (int i2 = 0; i2 < 2; ++i2){
        int i = half * 2 + i2;
        #pragma unroll
        for (int rr = 0; rr < 4; ++rr)
          #pragma unroll
          for (int j = 0; j < 4; ++j)
            stgf[(i2 * 16 + lg_ * 4 + rr) * 64 + j * 16 + lr_] = gelu_f(acc[i][j][rr] + bsv[j]);
      }
      #pragma unroll
      for (int pass = 0; pass < 8; ++pass){
        int chunk = pass * 64 + lane;
        int row = chunk >> 4, sub = chunk & 15;
        float4v vv = *(const float4v*)(stgf + row * 64 + sub * 4);
        int grow = m0 + wr * 64 + half * 32 + row;
        if (grow < HW_)
          *(float4v*)(of + ((size_t)b * HW_ + grow) * 512 + colbase + sub * 4) = vv;
      }
    }
  } else {
    #pragma unroll
    for (int i = 0; i < 4; ++i)
      #pragma unroll
      for (int rr = 0; rr < 4; ++rr)
        #pragma unroll
        for (int j = 0; j < 4; ++j){
          float v = acc[i][j][rr] + bsv[j];
          stw[(i * 16 + lg_ * 4 + rr) * 64 + j * 16 + lr_] = f2bf(v);
        }
    unsigned short* optr = (MODE == 1 || n0 < 512) ? o0 : o1;
    const int coloff = (MODE == 1 || n0 < 512) ? colbase : (colbase - 512);
    #pragma unroll
    for (int pass = 0; pass < 8; ++pass){
      int chunk = pass * 64 + lane;
      int row = chunk >> 3, sub = chunk & 7;
      ushort8v vv = *(const ushort8v*)(stw + row * 64 + sub * 8);
      int grow = m0 + wr * 64 + row;
      if (grow < HW_)
        *(ushort8v*)(optr + ((size_t)b * HW_ + grow) * 512 + coloff + sub * 8) = vv;
    }
  }
}

// --------------------------- IN stats stage-2 (w; 29x2 partials) ------------
__global__ void k_stats_p2b(const float2* __restrict__ partial, float2* __restrict__ stats){
  const int b = blockIdx.x;
  const int c = threadIdx.x;   // 512
  float s = 0.f, q = 0.f;
  for (int mt = 0; mt < 29; ++mt){
    float2 p0 = partial[((size_t)b * 29 + mt) * 1024 + c];
    float2 p1 = partial[((size_t)b * 29 + mt) * 1024 + 512 + c];
    s += p0.x + p1.x; q += p0.y + p1.y;
  }
  float mean = s * (1.0f / (float)HW_);
  float var  = q * (1.0f / (float)HW_) - mean * mean;
  stats[(size_t)b * 512 + c] = make_float2(mean, rsqrtf(var + 1e-5f));
}

// --------------------------- attention prep (+fused q-stats) ----------------
__global__ void k_prep(const float2* __restrict__ partial, const float* __restrict__ k_s,
                       const float* __restrict__ v_s, const float* __restrict__ l_mask,
                       unsigned short* __restrict__ k2, unsigned short* __restrict__ v2,
                       float* __restrict__ e_s)
{
  const int b = blockIdx.x;
  const int tid = threadIdx.x;
  __shared__ float wred[4][NL_];
  __shared__ float2 stats_sh[512];

  #pragma unroll
  for (int half = 0; half < 2; ++half){
    int c = tid + half * 256;
    float s = 0.f, q = 0.f;
    for (int mt = 0; mt < 29; ++mt){
      float2 p0 = partial[((size_t)b * 29 + mt) * 1024 + c];
      float2 p1 = partial[((size_t)b * 29 + mt) * 1024 + 512 + c];
      s += p0.x + p1.x; q += p0.y + p1.y;
    }
    float mean = s * (1.0f / (float)HW_);
    float var  = q * (1.0f / (float)HW_) - mean * mean;
    stats_sh[c] = make_float2(mean, rsqrtf(var + 1e-5f));
  }
  __syncthreads();

  float part[NL_];
  #pragma unroll
  for (int n = 0; n < NL_; ++n) part[n] = 0.f;
  #pragma unroll
  for (int half = 0; half < 2; ++half){
    int c = tid + half * 256;
    float2 st = stats_sh[c];
    float ms = st.x * st.y;
    const float* row = k_s + ((size_t)b * 512 + c) * NL_;
    #pragma unroll
    for (int n = 0; n < NL_; ++n) part[n] = fmaf(ms, row[n], part[n]);
  }
  #pragma unroll
  for (int n = 0; n < NL_; ++n){
    float v = part[n];
    v += __shfl_xor(v, 1);  v += __shfl_xor(v, 2);  v += __shfl_xor(v, 4);
    v += __shfl_xor(v, 8);  v += __shfl_xor(v, 16); v += __shfl_xor(v, 32);
    part[n] = v;
  }
  if ((tid & 63) == 0){
    #pragma unroll
    for (int n = 0; n < NL_; ++n) wred[tid >> 6][n] = part[n];
  }
  __syncthreads();
  if (tid < 32){
    float e;
    if (tid < NL_){
      float dsum = wred[0][tid] + wred[1][tid] + wred[2][tid] + wred[3][tid];
      e = -dsum - 10000.0f * (1.0f - l_mask[b * NL_ + tid]);
    } else {
      e = -1e30f;
    }
    e_s[b * 32 + tid] = e;
  }

  for (int i = tid; i < 16384; i += 256){
    int h = i >> 11, t = (i >> 10) & 1, s = (i >> 9) & 1;
    int l = (i >> 3) & 63, j = i & 7;
    int r = l & 15, g = l >> 4;
    int n = t * 16 + r;
    int c = h * 64 + s * 32 + g * 8 + j;
    unsigned short val = 0;
    if (n < NL_){
      float inv = stats_sh[c].y;
      val = f2bf(inv * k_s[((size_t)b * 512 + c) * NL_ + n]);
    }
    k2[(size_t)b * 16384 + i] = val;
  }
  for (int i = tid; i < 16384; i += 256){
    int h = i >> 11, ct = (i >> 9) & 3;
    int l = (i >> 3) & 63, j = i & 7;
    int r = l & 15, g = l >> 4;
    int n = g * 8 + j;
    int c = h * 64 + ct * 16 + r;
    unsigned short val = 0;
    if (n < NL_) val = f2bf(v_s[((size_t)b * 512 + c) * NL_ + n]);
    v2[(size_t)b * 16384 + i] = val;
  }
}

// --------------------------- attention (MFMA, swapped-QK) -------------------
__global__ __launch_bounds__(256) void k_attn2(unsigned short* __restrict__ qraw,
    const unsigned short* __restrict__ k2, const unsigned short* __restrict__ v2,
    const float* __restrict__ e_s)
{
  const int b = blockIdx.y;
  const int w = threadIdx.x >> 6;
  const int tile = blockIdx.x * 4 + w;
  __shared__ __align__(16) unsigned short p_sh[4][16 * 32];
  __shared__ __align__(16) unsigned short o_sh[4][16 * 72];
  if (tile >= 225) return;
  const int lane = threadIdx.x & 63;
  const int r = lane & 15, g = lane >> 4;
  const int row0 = tile * 16;

  float4v e0 = *(const float4v*)(e_s + b * 32 + g * 4);
  float4v e1 = *(const float4v*)(e_s + b * 32 + 16 + g * 4);

  bf16x8 qf[8][2];
  const unsigned short* qbase = qraw + ((size_t)(b * HW_ + row0 + r) * 512) + g * 8;
  #pragma unroll
  for (int h = 0; h < 8; ++h)
    #pragma unroll
    for (int s = 0; s < 2; ++s)
      qf[h][s] = *(const bf16x8*)(qbase + h * 64 + s * 32);

  const unsigned short* kb = k2 + (size_t)b * 16384 + lane * 8;
  const unsigned short* vb = v2 + (size_t)b * 16384 + lane * 8;
  unsigned short* psh = &p_sh[w][0];
  unsigned short* osh = &o_sh[w][0];

  for (int h = 0; h < 8; ++h){
    bf16x8 kf00 = *(const bf16x8*)(kb + (h * 4 + 0) * 512);
    bf16x8 kf01 = *(const bf16x8*)(kb + (h * 4 + 1) * 512);
    bf16x8 kf10 = *(const bf16x8*)(kb + (h * 4 + 2) * 512);
    bf16x8 kf11 = *(const bf16x8*)(kb + (h * 4 + 3) * 512);
    f32x4 c0 = (f32x4){0.f,0.f,0.f,0.f};
    f32x4 c1 = (f32x4){0.f,0.f,0.f,0.f};
    c0 = __builtin_amdgcn_mfma_f32_16x16x32_bf16(kf00, qf[h][0], c0, 0, 0, 0);
    c0 = __builtin_amdgcn_mfma_f32_16x16x32_bf16(kf01, qf[h][1], c0, 0, 0, 0);
    c1 = __builtin_amdgcn_mfma_f32_16x16x32_bf16(kf10, qf[h][0], c1, 0, 0, 0);
    c1 = __builtin_amdgcn_mfma_f32_16x16x32_bf16(kf11, qf[h][1], c1, 0, 0, 0);

    float l0[4], l1[4];
    #pragma unroll
    for (int i = 0; i < 4; ++i){ l0[i] = c0[i] + e0[i]; l1[i] = c1[i] + e1[i]; }
    float m = fmaxf(fmaxf(fmaxf(l0[0], l0[1]), fmaxf(l0[2], l0[3])),
                    fmaxf(fmaxf(l1[0], l1[1]), fmaxf(l1[2], l1[3])));
    m = fmaxf(m, __shfl_xor(m, 16));
    m = fmaxf(m, __shfl_xor(m, 32));
    float p0[4], p1[4];
    #pragma unroll
    for (int i = 0; i < 4; ++i){ p0[i] = __expf(l0[i] - m); p1[i] = __expf(l1[i] - m); }

    uint2v pw0, pw1;
    pw0.x = pack2bf(p0[0], p0[1]); pw0.y = pack2bf(p0[2], p0[3]);
    pw1.x = pack2bf(p1[0], p1[1]); pw1.y = pack2bf(p1[2], p1[3]);
    float sum = bf2f((unsigned short)(pw0.x & 0xffff)) + bf2f((unsigned short)(pw0.x >> 16))
              + bf2f((unsigned short)(pw0.y & 0xffff)) + bf2f((unsigned short)(pw0.y >> 16))
              + bf2f((unsigned short)(pw1.x & 0xffff)) + bf2f((unsigned short)(pw1.x >> 16))
              + bf2f((unsigned short)(pw1.y & 0xffff)) + bf2f((unsigned short)(pw1.y >> 16));
    sum += __shfl_xor(sum, 16);
    sum += __shfl_xor(sum, 32);
    float inv = 1.0f / sum;

    *(uint2v*)(psh + r * 32 + 4 * g)      = pw0;
    *(uint2v*)(psh + r * 32 + 16 + 4 * g) = pw1;
    bf16x8 pfrag = *(const bf16x8*)(psh + r * 32 + g * 8);

    f32x4 dd[4];
    #pragma unroll
    for (int ct = 0; ct < 4; ++ct){
      bf16x8 vf = *(const bf16x8*)(vb + (h * 4 + ct) * 512);
      f32x4 z = (f32x4){0.f,0.f,0.f,0.f};
      dd[ct] = __builtin_amdgcn_mfma_f32_16x16x32_bf16(vf, pfrag, z, 0, 0, 0);
    }
    #pragma unroll
    for (int ct = 0; ct < 4; ++ct){
      uint2v ow;
      ow.x = pack2bf(dd[ct][0] * inv, dd[ct][1] * inv);
      ow.y = pack2bf(dd[ct][2] * inv, dd[ct][3] * inv);
      *(uint2v*)(osh + r * 72 + ct * 16 + 4 * g) = ow;
    }
    int frow = lane >> 2, fch = lane & 3;
    ushort8v t0 = *(const ushort8v*)(osh + frow * 72 + fch * 16);
    ushort8v t1 = *(const ushort8v*)(osh + frow * 72 + fch * 16 + 8);
    unsigned short* gdst = qraw + ((size_t)(b * HW_ + row0 + frow) * 512) + h * 64 + fch * 16;
    *(ushort8v*)(gdst)     = t0;
    *(ushort8v*)(gdst + 8) = t1;
  }
}

// --------------------------- h = gelu(vis) * IN(yw) (in-place over yw) ------
__global__ __launch_bounds__(256) void k_hmul(unsigned short* __restrict__ yw,
    const unsigned short* __restrict__ visb, const float2* __restrict__ stats)
{
  const int b = blockIdx.y, blk = blockIdx.x;
  const int w = threadIdx.x >> 6, lane = threadIdx.x & 63;
  const int c0 = lane * 8;
  float mean[8], inv[8];
  #pragma unroll
  for (int j = 0; j < 8; ++j){
    float2 st = stats[(size_t)b * 512 + c0 + j];
    mean[j] = st.x; inv[j] = st.y;
  }
  for (int it = 0; it < 30; ++it){
    int row = blk * 120 + it * 4 + w;
    size_t off = ((size_t)b * HW_ + row) * 512 + c0;
    ushort8v yv = *(const ushort8v*)(yw + off);
    ushort8v vv = *(const ushort8v*)(visb + off);
    ushort8v hv;
    #pragma unroll
    for (int j = 0; j < 8; ++j){
      float lang = (bf2f(yv[j]) - mean[j]) * inv[j];
      float visg = gelu_f(bf2f(vv[j]));
      hv[j] = f2bf(visg * lang);
    }
    *(ushort8v*)(yw + off) = hv;
  }
}

// ---------------------------------------------------------------------------
extern "C" void kernel_launch(void* const* d_in, const int* in_sizes, int n_in,
                              void* d_out, int out_size, void* d_ws, size_t ws_size,
                              hipStream_t stream)
{
  const float* x     = (const float*)d_in[0];
  const float* l     = (const float*)d_in[1];
  const float* lmask = (const float*)d_in[2];
  const float* Wvis  = (const float*)d_in[3];
  const float* bvis  = (const float*)d_in[4];
  const float* Wq    = (const float*)d_in[5];
  const float* bq    = (const float*)d_in[6];
  const float* Wk    = (const float*)d_in[7];
  const float* bk    = (const float*)d_in[8];
  const float* Wval  = (const float*)d_in[9];
  const float* bval  = (const float*)d_in[10];
  const float* Ww    = (const float*)d_in[11];
  const float* bw    = (const float*)d_in[12];
  const float* Wmm   = (const float*)d_in[13];
  const float* bmm   = (const float*)d_in[14];
  float* out = (float*)d_out;

  char* ws = (char*)d_ws;
  if (ws_size < 240517120ull) return;
  unsigned short* visb  = (unsigned short*)(ws + 58982400);
  unsigned short* qraw  = (unsigned short*)(ws + 117964800);
  unsigned short* yw    = (unsigned short*)(ws + 176947200);
  unsigned short* wcat  = (unsigned short*)(ws + 235929600);
  unsigned short* wwb   = (unsigned short*)(ws + 236978176);
  unsigned short* wmmb  = (unsigned short*)(ws + 237502464);
  float*  k_s    = (float*)(ws + 238026752);
  float*  v_s    = (float*)(ws + 238682112);
  float2* stats_w= (float2*)(ws + 240451584);
  unsigned short* k2 = (unsigned short*)(ws + 0);          // 512 KB (old xb region)
  unsigned short* v2 = (unsigned short*)(ws + 524288);     // 512 KB
  float*          e_s = (float*)(ws + 1048576);            // 2 KB
  float2* partial_q = (float2*)(ws + 176947200);           // yw region, 3.8 MB (dead during gemm0)
  float2* partial_w = (float2*)(ws + 1052672);             // old-xb region, 3.8 MB (dead during gemm1)

  // 1) weight conversions only (x is converted inside gemm0)
  k_cvt_w<<<512, 256, 0, stream>>>(Wvis, Wq, Ww, Wmm, wcat, wwb, wmmb);

  // 2) K/V projections (mask + bias + 1/sqrt(KC) folded)
  k_kv<<<dim3(16, B_), 256, 0, stream>>>(l, lmask, Wk, bk, Wval, bval, k_s, v_s);

  // 3) dual GEMM from f32 x: visb = x@Wvis^T+bvis (RAW), qraw = x@Wq^T+bq (+ q-stats)
  k_gemm<0, 8, true, true><<<29 * 8 * B_, 256, 0, stream>>>(nullptr, x, wcat, bvis, bq, visb, qraw, nullptr, partial_q);

  // 4) prep: q-stats finalize (in LDS) + MFMA fragments + e_s
  k_prep<<<B_, 256, 0, stream>>>(partial_q, k_s, v_s, lmask, k2, v2, e_s);

  // 5) MFMA attention, in-place over qraw
  k_attn2<<<dim3(57, B_), 256, 0, stream>>>(qraw, k2, v2, e_s);

  // 6) yw = attn_out @ Ww^T + bw  (+ w-stats partials)
  k_gemm<1, 4, true, false><<<29 * 4 * B_, 256, 0, stream>>>(qraw, x, wwb, bw, nullptr, yw, nullptr, nullptr, partial_w);

  // 7) IN stats for yw (stage 2)
  k_stats_p2b<<<B_, 512, 0, stream>>>(partial_w, stats_w);

  // 8) h = gelu(vis) * IN(yw)   (in-place over yw)
  k_hmul<<<dim3(30, B_), 256, 0, stream>>>(yw, visb, stats_w);

  // 9) out = gelu(h @ Wmm^T + bmm)  (f32)
  k_gemm<2, 4, false, false><<<29 * 4 * B_, 256, 0, stream>>>(yw, x, wmmb, bmm, nullptr, nullptr, nullptr, out, nullptr);
}

// Round 14
// 378.410 us; speedup vs baseline: 2.1751x; 2.1751x over previous
//
#include <hip/hip_runtime.h>

// ---------------------------------------------------------------------------
// PWAM fused pipeline, bf16 MFMA GEMMs + MFMA attention (swapped-QK, IN folded)
// R14: R13 with the spill bug fixed — __launch_bounds__(256,4) (VGPR cap 128,
//      no scratch spills; R13's (256,5) cap=102 forced 1.3GB of spill traffic).
//      Keeps: cvt-x fused into gemm0 (AF32 reg-staged A), 32KB LDS, per-wr
//      stats partials.
// B=16, HW=3600, D=KC=VC=512, LC=768, NL=20, H=8
// ---------------------------------------------------------------------------

#define B_   16
#define HW_  3600
#define D_   512
#define LC_  768
#define NL_  20

typedef __attribute__((ext_vector_type(8))) __bf16 bf16x8;
typedef __attribute__((ext_vector_type(4))) float f32x4;
typedef __attribute__((ext_vector_type(4))) float float4v;
typedef __attribute__((ext_vector_type(8))) unsigned short ushort8v;
typedef __attribute__((ext_vector_type(4))) unsigned short ushort4v;
typedef __attribute__((ext_vector_type(2))) unsigned int uint2v;

static __device__ __forceinline__ float bf2f(unsigned short u){
  unsigned int x = ((unsigned int)u) << 16; float f;
  __builtin_memcpy(&f, &x, 4); return f;
}
static __device__ __forceinline__ unsigned short f2bf(float f){
  __bf16 h = (__bf16)f;
  unsigned short u; __builtin_memcpy(&u, &h, 2); return u;
}
static __device__ __forceinline__ unsigned int pack2bf(float lo, float hi){
  return (unsigned int)f2bf(lo) | ((unsigned int)f2bf(hi) << 16);
}
// gelu(x) = 0.5x(1+erf(x/sqrt2)); erf via A&S 7.1.26 (|err|<=1.5e-7), hw exp.
static __device__ __forceinline__ float gelu_f(float x){
  float z  = x * 0.7071067811865476f;
  float az = fabsf(z);
  float t = 1.0f / fmaf(0.3275911f, az, 1.0f);
  float p = fmaf(1.061405429f, t, -1.453152027f);
  p = fmaf(p, t, 1.421413741f);
  p = fmaf(p, t, -0.284496736f);
  p = fmaf(p, t, 0.254829592f);
  p = p * t;
  float er = 1.0f - p * __expf(-az * az);
  er = copysignf(er, z);
  return 0.5f * x * (1.0f + er);
}

// --------------------------- weights f32 -> bf16 ----------------------------
__global__ void k_cvt_w(const float* __restrict__ Wvis, const float* __restrict__ Wq,
                        const float* __restrict__ Ww,   const float* __restrict__ Wmm,
                        unsigned short* __restrict__ wcat,
                        unsigned short* __restrict__ wwb, unsigned short* __restrict__ wmmb){
  const int TOT = 4 * 65536;
  int i = blockIdx.x * 256 + threadIdx.x;
  int stride = gridDim.x * 256;
  for (; i < TOT; i += stride){
    int seg = i >> 16, o = i & 0xFFFF;
    const float4v* s; ushort4v* dp;
    if      (seg == 0){ s = (const float4v*)Wvis + o; dp = (ushort4v*)wcat + o; }
    else if (seg == 1){ s = (const float4v*)Wq   + o; dp = (ushort4v*)wcat + 65536 + o; }
    else if (seg == 2){ s = (const float4v*)Ww   + o; dp = (ushort4v*)wwb + o; }
    else              { s = (const float4v*)Wmm  + o; dp = (ushort4v*)wmmb + o; }
    float4v v = *s;
    ushort4v u;
    u.x = f2bf(v.x); u.y = f2bf(v.y); u.z = f2bf(v.z); u.w = f2bf(v.w);
    *dp = u;
  }
}

// --------------------------- K/V projections (tiny) -------------------------
__global__ void k_kv(const float* __restrict__ l, const float* __restrict__ l_mask,
                     const float* __restrict__ Wk, const float* __restrict__ bk,
                     const float* __restrict__ Wval, const float* __restrict__ bval,
                     float* __restrict__ k_s, float* __restrict__ v_s){
  const int b = blockIdx.y;
  const int part = blockIdx.x;
  const bool isK = part < 8;
  const int c0 = (part & 7) * 64;
  const float* W  = isK ? Wk : Wval;
  const float* bi = isK ? bk : bval;
  float* outp = isK ? k_s : v_s;

  __shared__ float l_sh[LC_ * NL_];
  for (int i = threadIdx.x; i < LC_ * NL_; i += 256)
    l_sh[i] = l[(size_t)b * LC_ * NL_ + i];
  __syncthreads();

  const int tid = threadIdx.x;
  const int cl = tid >> 2;
  const int q  = tid & 3;
  const int c  = c0 + cl;
  const float* wrow = W + (size_t)c * LC_;
  float acc[5] = {0.f,0.f,0.f,0.f,0.f};
  for (int i = 0; i < LC_; ++i){
    float wv = wrow[i];
    const float* lr = l_sh + i * NL_ + q * 5;
    acc[0] = fmaf(wv, lr[0], acc[0]);
    acc[1] = fmaf(wv, lr[1], acc[1]);
    acc[2] = fmaf(wv, lr[2], acc[2]);
    acc[3] = fmaf(wv, lr[3], acc[3]);
    acc[4] = fmaf(wv, lr[4], acc[4]);
  }
  const float bb = bi[c];
  #pragma unroll
  for (int n5 = 0; n5 < 5; ++n5){
    int n = q * 5 + n5;
    float m = l_mask[b * NL_ + n];
    float val = (acc[n5] + bb) * m;
    if (isK) val *= 0.04419417382415922f;   // 1/sqrt(512) folded into K
    outp[((size_t)b * 512 + c) * NL_ + n] = val;
  }
}

// --------------------------- GEMM (bf16 MFMA, 128x128 tile) -----------------
// 2-buffer LDS = 32KB, 4 blocks/CU (VGPR cap 128 -> no spills). R6 sync
// discipline. XOR bank swizzle both sides. AF32: A from f32 global via regs.
// MODE 0: dual out (NT=8): n<512 -> o0=bf16(v) RAW; else o1=bf16(v)
// MODE 1: o0 = bf16(v);  MODE 2: of = gelu(v) f32
template<int MODE, int NT, bool STATS, bool AF32>
__global__ __launch_bounds__(256, 4) void k_gemm(
    const unsigned short* __restrict__ A,
    const float* __restrict__ Afp,
    const unsigned short* __restrict__ Bm,
    const float* __restrict__ bias0, const float* __restrict__ bias1,
    unsigned short* __restrict__ o0, unsigned short* __restrict__ o1,
    float* __restrict__ of, float2* __restrict__ partial)
{
  __shared__ __align__(16) unsigned short smem[2][2][128 * 32];  // exactly 32 KB

  const int nwg = 29 * NT * B_;
  const int per = nwg >> 3;
  const int d = blockIdx.x;
  const int g = (d & 7) * per + (d >> 3);
  constexpr int NSH = (NT == 8) ? 3 : 2;
  const int nt = g & (NT - 1);
  const int rem = g >> NSH;
  const int mt = rem % 29;
  const int b  = rem / 29;

  const int m0 = mt * 128;
  const int n0 = nt * 128;
  const int tid = threadIdx.x;
  const int w = tid >> 6, lane = tid & 63;
  const int wr = w >> 1, wc = w & 1;
  const int lr_ = lane & 15, lg_ = lane >> 4;
  const int mvalid = HW_ - m0;
  const unsigned short* Ab = A + (size_t)b * HW_ * 512;
  const float* Afb = Afp + (size_t)b * HW_ * 512;

  f32x4 acc[4][4];
  #pragma unroll
  for (int i = 0; i < 4; ++i)
    #pragma unroll
    for (int j = 0; j < 4; ++j)
      acc[i][j] = (f32x4){0.f, 0.f, 0.f, 0.f};

  auto stageA = [&](int kt, int buf){
    const int k0 = kt * 32;
    #pragma unroll
    for (int s = 0; s < 2; ++s){
      int chunk = s * 256 + tid;
      int row = chunk >> 2, part = chunk & 3;
      int psrc = part ^ ((row >> 1) & 3);
      int grow = row < mvalid ? row : (mvalid - 1);
      const unsigned short* gsrc = Ab + ((size_t)(m0 + grow) * 512 + k0 + psrc * 8);
      unsigned short* ldst = &smem[0][buf][(s * 256 + w * 64) * 8];
      __builtin_amdgcn_global_load_lds((const __attribute__((address_space(1))) void*)gsrc,
                                       (__attribute__((address_space(3))) void*)ldst, 16, 0, 0);
    }
  };
  float4v Ar[2][2];
  auto issueA = [&](int kt){
    const int k0 = kt * 32;
    #pragma unroll
    for (int s = 0; s < 2; ++s){
      int chunk = s * 256 + tid;
      int row = chunk >> 2, part = chunk & 3;
      int psrc = part ^ ((row >> 1) & 3);
      int grow = row < mvalid ? row : (mvalid - 1);
      const float* gs = Afb + ((size_t)(m0 + grow) * 512 + k0 + psrc * 8);
      Ar[s][0] = *(const float4v*)(gs);
      Ar[s][1] = *(const float4v*)(gs + 4);
    }
  };
  auto writeA = [&](int buf){
    #pragma unroll
    for (int s = 0; s < 2; ++s){
      ushort8v o;
      o[0] = f2bf(Ar[s][0].x); o[1] = f2bf(Ar[s][0].y);
      o[2] = f2bf(Ar[s][0].z); o[3] = f2bf(Ar[s][0].w);
      o[4] = f2bf(Ar[s][1].x); o[5] = f2bf(Ar[s][1].y);
      o[6] = f2bf(Ar[s][1].z); o[7] = f2bf(Ar[s][1].w);
      *(ushort8v*)(&smem[0][buf][(s * 256 + tid) * 8]) = o;
    }
  };
  auto stageB = [&](int kt, int buf){
    const int k0 = kt * 32;
    #pragma unroll
    for (int s = 0; s < 2; ++s){
      int chunk = s * 256 + tid;
      int row = chunk >> 2, part = chunk & 3;
      int psrc = part ^ ((row >> 1) & 3);
      const unsigned short* gsrc = Bm + ((size_t)(n0 + row) * 512 + k0 + psrc * 8);
      unsigned short* ldst = &smem[1][buf][(s * 256 + w * 64) * 8];
      __builtin_amdgcn_global_load_lds((const __attribute__((address_space(1))) void*)gsrc,
                                       (__attribute__((address_space(3))) void*)ldst, 16, 0, 0);
    }
  };

  auto compute = [&](int buf){
    const unsigned short* lA = &smem[0][buf][(wr * 64) * 32];
    const unsigned short* lB = &smem[1][buf][(wc * 64) * 32];
    const int kx = (lg_ ^ ((lr_ >> 1) & 3)) * 8;
    bf16x8 av[4], bv[4];
    #pragma unroll
    for (int i = 0; i < 4; ++i) av[i] = *(const bf16x8*)(lA + (i * 16 + lr_) * 32 + kx);
    #pragma unroll
    for (int j = 0; j < 4; ++j) bv[j] = *(const bf16x8*)(lB + (j * 16 + lr_) * 32 + kx);
    #pragma unroll
    for (int i = 0; i < 4; ++i)
      #pragma unroll
      for (int j = 0; j < 4; ++j)
        acc[i][j] = __builtin_amdgcn_mfma_f32_16x16x32_bf16(av[i], bv[j], acc[i][j], 0, 0, 0);
  };

  // prologue: tile 0
  if (AF32){
    issueA(0);
    stageB(0, 0);
    writeA(0);            // compiler inserts vmcnt for Ar deps
  } else {
    stageA(0, 0);
    stageB(0, 0);
  }

  #pragma unroll
  for (int t = 0; t < 16; ++t){
    asm volatile("s_waitcnt lgkmcnt(0)" ::: "memory");
    __builtin_amdgcn_sched_barrier(0);
    asm volatile("s_waitcnt vmcnt(0)" ::: "memory");
    __builtin_amdgcn_s_barrier();
    __builtin_amdgcn_sched_barrier(0);
    const int nb = (t + 1) & 1;
    if (t < 15){
      if (AF32) issueA(t + 1);
      else      stageA(t + 1, nb);
      stageB(t + 1, nb);
      if (AF32) __builtin_amdgcn_sched_barrier(0);   // pin load issue before MFMAs
    }
    compute(t & 1);
    if (AF32 && t < 15) writeA(nb);   // vmcnt waits auto-inserted for Ar
  }

  // ---- epilogue ----
  const int colbase = n0 + wc * 64;
  float bsv[4];
  #pragma unroll
  for (int j = 0; j < 4; ++j){
    int col = colbase + j * 16 + lr_;
    if (MODE == 0) bsv[j] = (col < 512) ? bias0[col] : bias1[col - 512];
    else           bsv[j] = bias0[col];
  }
  const bool do_stats = STATS && (MODE != 0 || n0 >= 512);

  if (STATS && do_stats){
    float colsum[4] = {0.f,0.f,0.f,0.f}, colsq[4] = {0.f,0.f,0.f,0.f};
    #pragma unroll
    for (int i = 0; i < 4; ++i){
      int rowb = m0 + wr * 64 + i * 16 + lg_ * 4;
      #pragma unroll
      for (int rr = 0; rr < 4; ++rr){
        if (rowb + rr < HW_){
          #pragma unroll
          for (int j = 0; j < 4; ++j){
            float v = acc[i][j][rr] + bsv[j];
            colsum[j] += v;
            colsq[j]  = fmaf(v, v, colsq[j]);
          }
        }
      }
    }
    #pragma unroll
    for (int j = 0; j < 4; ++j){
      colsum[j] += __shfl_xor(colsum[j], 16);
      colsum[j] += __shfl_xor(colsum[j], 32);
      colsq[j]  += __shfl_xor(colsq[j], 16);
      colsq[j]  += __shfl_xor(colsq[j], 32);
    }
    if (lg_ == 0){
      #pragma unroll
      for (int j = 0; j < 4; ++j){
        int gcol = colbase + j * 16 + lr_ - (MODE == 0 ? 512 : 0);
        partial[((size_t)b * 29 + mt) * 1024 + wr * 512 + gcol] =
          make_float2(colsum[j], colsq[j]);
      }
    }
  }

  __syncthreads();   // K-loop LDS reads done -> smem reusable for C staging

  unsigned short* stw = &smem[0][0][0] + w * 4096;   // 8KB wave-private

  if (MODE == 2){
    float* stgf = (float*)stw;
    #pragma unroll
    for (int half = 0; half < 2; ++half){
      #pragma unroll
      for (int i2 = 0; i2 < 2; ++i2){
        int i = half * 2 + i2;
        #pragma unroll
        for (int rr = 0; rr < 4; ++rr)
          #pragma unroll
          for (int j = 0; j < 4; ++j)
            stgf[(i2 * 16 + lg_ * 4 + rr) * 64 + j * 16 + lr_] = gelu_f(acc[i][j][rr] + bsv[j]);
      }
      #pragma unroll
      for (int pass = 0; pass < 8; ++pass){
        int chunk = pass * 64 + lane;
        int row = chunk >> 4, sub = chunk & 15;
        float4v vv = *(const float4v*)(stgf + row * 64 + sub * 4);
        int grow = m0 + wr * 64 + half * 32 + row;
        if (grow < HW_)
          *(float4v*)(of + ((size_t)b * HW_ + grow) * 512 + colbase + sub * 4) = vv;
      }
    }
  } else {
    #pragma unroll
    for (int i = 0; i < 4; ++i)
      #pragma unroll
      for (int rr = 0; rr < 4; ++rr)
        #pragma unroll
        for (int j = 0; j < 4; ++j){
          float v = acc[i][j][rr] + bsv[j];
          stw[(i * 16 + lg_ * 4 + rr) * 64 + j * 16 + lr_] = f2bf(v);
        }
    unsigned short* optr = (MODE == 1 || n0 < 512) ? o0 : o1;
    const int coloff = (MODE == 1 || n0 < 512) ? colbase : (colbase - 512);
    #pragma unroll
    for (int pass = 0; pass < 8; ++pass){
      int chunk = pass * 64 + lane;
      int row = chunk >> 3, sub = chunk & 7;
      ushort8v vv = *(const ushort8v*)(stw + row * 64 + sub * 8);
      int grow = m0 + wr * 64 + row;
      if (grow < HW_)
        *(ushort8v*)(optr + ((size_t)b * HW_ + grow) * 512 + coloff + sub * 8) = vv;
    }
  }
}

// --------------------------- IN stats stage-2 (w; 29x2 partials) ------------
__global__ void k_stats_p2b(const float2* __restrict__ partial, float2* __restrict__ stats){
  const int b = blockIdx.x;
  const int c = threadIdx.x;   // 512
  float s = 0.f, q = 0.f;
  for (int mt = 0; mt < 29; ++mt){
    float2 p0 = partial[((size_t)b * 29 + mt) * 1024 + c];
    float2 p1 = partial[((size_t)b * 29 + mt) * 1024 + 512 + c];
    s += p0.x + p1.x; q += p0.y + p1.y;
  }
  float mean = s * (1.0f / (float)HW_);
  float var  = q * (1.0f / (float)HW_) - mean * mean;
  stats[(size_t)b * 512 + c] = make_float2(mean, rsqrtf(var + 1e-5f));
}

// --------------------------- attention prep (+fused q-stats) ----------------
__global__ void k_prep(const float2* __restrict__ partial, const float* __restrict__ k_s,
                       const float* __restrict__ v_s, const float* __restrict__ l_mask,
                       unsigned short* __restrict__ k2, unsigned short* __restrict__ v2,
                       float* __restrict__ e_s)
{
  const int b = blockIdx.x;
  const int tid = threadIdx.x;
  __shared__ float wred[4][NL_];
  __shared__ float2 stats_sh[512];

  #pragma unroll
  for (int half = 0; half < 2; ++half){
    int c = tid + half * 256;
    float s = 0.f, q = 0.f;
    for (int mt = 0; mt < 29; ++mt){
      float2 p0 = partial[((size_t)b * 29 + mt) * 1024 + c];
      float2 p1 = partial[((size_t)b * 29 + mt) * 1024 + 512 + c];
      s += p0.x + p1.x; q += p0.y + p1.y;
    }
    float mean = s * (1.0f / (float)HW_);
    float var  = q * (1.0f / (float)HW_) - mean * mean;
    stats_sh[c] = make_float2(mean, rsqrtf(var + 1e-5f));
  }
  __syncthreads();

  float part[NL_];
  #pragma unroll
  for (int n = 0; n < NL_; ++n) part[n] = 0.f;
  #pragma unroll
  for (int half = 0; half < 2; ++half){
    int c = tid + half * 256;
    float2 st = stats_sh[c];
    float ms = st.x * st.y;
    const float* row = k_s + ((size_t)b * 512 + c) * NL_;
    #pragma unroll
    for (int n = 0; n < NL_; ++n) part[n] = fmaf(ms, row[n], part[n]);
  }
  #pragma unroll
  for (int n = 0; n < NL_; ++n){
    float v = part[n];
    v += __shfl_xor(v, 1);  v += __shfl_xor(v, 2);  v += __shfl_xor(v, 4);
    v += __shfl_xor(v, 8);  v += __shfl_xor(v, 16); v += __shfl_xor(v, 32);
    part[n] = v;
  }
  if ((tid & 63) == 0){
    #pragma unroll
    for (int n = 0; n < NL_; ++n) wred[tid >> 6][n] = part[n];
  }
  __syncthreads();
  if (tid < 32){
    float e;
    if (tid < NL_){
      float dsum = wred[0][tid] + wred[1][tid] + wred[2][tid] + wred[3][tid];
      e = -dsum - 10000.0f * (1.0f - l_mask[b * NL_ + tid]);
    } else {
      e = -1e30f;
    }
    e_s[b * 32 + tid] = e;
  }

  for (int i = tid; i < 16384; i += 256){
    int h = i >> 11, t = (i >> 10) & 1, s = (i >> 9) & 1;
    int l = (i >> 3) & 63, j = i & 7;
    int r = l & 15, g = l >> 4;
    int n = t * 16 + r;
    int c = h * 64 + s * 32 + g * 8 + j;
    unsigned short val = 0;
    if (n < NL_){
      float inv = stats_sh[c].y;
      val = f2bf(inv * k_s[((size_t)b * 512 + c) * NL_ + n]);
    }
    k2[(size_t)b * 16384 + i] = val;
  }
  for (int i = tid; i < 16384; i += 256){
    int h = i >> 11, ct = (i >> 9) & 3;
    int l = (i >> 3) & 63, j = i & 7;
    int r = l & 15, g = l >> 4;
    int n = g * 8 + j;
    int c = h * 64 + ct * 16 + r;
    unsigned short val = 0;
    if (n < NL_) val = f2bf(v_s[((size_t)b * 512 + c) * NL_ + n]);
    v2[(size_t)b * 16384 + i] = val;
  }
}

// --------------------------- attention (MFMA, swapped-QK) -------------------
__global__ __launch_bounds__(256) void k_attn2(unsigned short* __restrict__ qraw,
    const unsigned short* __restrict__ k2, const unsigned short* __restrict__ v2,
    const float* __restrict__ e_s)
{
  const int b = blockIdx.y;
  const int w = threadIdx.x >> 6;
  const int tile = blockIdx.x * 4 + w;
  __shared__ __align__(16) unsigned short p_sh[4][16 * 32];
  __shared__ __align__(16) unsigned short o_sh[4][16 * 72];
  if (tile >= 225) return;
  const int lane = threadIdx.x & 63;
  const int r = lane & 15, g = lane >> 4;
  const int row0 = tile * 16;

  float4v e0 = *(const float4v*)(e_s + b * 32 + g * 4);
  float4v e1 = *(const float4v*)(e_s + b * 32 + 16 + g * 4);

  bf16x8 qf[8][2];
  const unsigned short* qbase = qraw + ((size_t)(b * HW_ + row0 + r) * 512) + g * 8;
  #pragma unroll
  for (int h = 0; h < 8; ++h)
    #pragma unroll
    for (int s = 0; s < 2; ++s)
      qf[h][s] = *(const bf16x8*)(qbase + h * 64 + s * 32);

  const unsigned short* kb = k2 + (size_t)b * 16384 + lane * 8;
  const unsigned short* vb = v2 + (size_t)b * 16384 + lane * 8;
  unsigned short* psh = &p_sh[w][0];
  unsigned short* osh = &o_sh[w][0];

  for (int h = 0; h < 8; ++h){
    bf16x8 kf00 = *(const bf16x8*)(kb + (h * 4 + 0) * 512);
    bf16x8 kf01 = *(const bf16x8*)(kb + (h * 4 + 1) * 512);
    bf16x8 kf10 = *(const bf16x8*)(kb + (h * 4 + 2) * 512);
    bf16x8 kf11 = *(const bf16x8*)(kb + (h * 4 + 3) * 512);
    f32x4 c0 = (f32x4){0.f,0.f,0.f,0.f};
    f32x4 c1 = (f32x4){0.f,0.f,0.f,0.f};
    c0 = __builtin_amdgcn_mfma_f32_16x16x32_bf16(kf00, qf[h][0], c0, 0, 0, 0);
    c0 = __builtin_amdgcn_mfma_f32_16x16x32_bf16(kf01, qf[h][1], c0, 0, 0, 0);
    c1 = __builtin_amdgcn_mfma_f32_16x16x32_bf16(kf10, qf[h][0], c1, 0, 0, 0);
    c1 = __builtin_amdgcn_mfma_f32_16x16x32_bf16(kf11, qf[h][1], c1, 0, 0, 0);

    float l0[4], l1[4];
    #pragma unroll
    for (int i = 0; i < 4; ++i){ l0[i] = c0[i] + e0[i]; l1[i] = c1[i] + e1[i]; }
    float m = fmaxf(fmaxf(fmaxf(l0[0], l0[1]), fmaxf(l0[2], l0[3])),
                    fmaxf(fmaxf(l1[0], l1[1]), fmaxf(l1[2], l1[3])));
    m = fmaxf(m, __shfl_xor(m, 16));
    m = fmaxf(m, __shfl_xor(m, 32));
    float p0[4], p1[4];
    #pragma unroll
    for (int i = 0; i < 4; ++i){ p0[i] = __expf(l0[i] - m); p1[i] = __expf(l1[i] - m); }

    uint2v pw0, pw1;
    pw0.x = pack2bf(p0[0], p0[1]); pw0.y = pack2bf(p0[2], p0[3]);
    pw1.x = pack2bf(p1[0], p1[1]); pw1.y = pack2bf(p1[2], p1[3]);
    float sum = bf2f((unsigned short)(pw0.x & 0xffff)) + bf2f((unsigned short)(pw0.x >> 16))
              + bf2f((unsigned short)(pw0.y & 0xffff)) + bf2f((unsigned short)(pw0.y >> 16))
              + bf2f((unsigned short)(pw1.x & 0xffff)) + bf2f((unsigned short)(pw1.x >> 16))
              + bf2f((unsigned short)(pw1.y & 0xffff)) + bf2f((unsigned short)(pw1.y >> 16));
    sum += __shfl_xor(sum, 16);
    sum += __shfl_xor(sum, 32);
    float inv = 1.0f / sum;

    *(uint2v*)(psh + r * 32 + 4 * g)      = pw0;
    *(uint2v*)(psh + r * 32 + 16 + 4 * g) = pw1;
    bf16x8 pfrag = *(const bf16x8*)(psh + r * 32 + g * 8);

    f32x4 dd[4];
    #pragma unroll
    for (int ct = 0; ct < 4; ++ct){
      bf16x8 vf = *(const bf16x8*)(vb + (h * 4 + ct) * 512);
      f32x4 z = (f32x4){0.f,0.f,0.f,0.f};
      dd[ct] = __builtin_amdgcn_mfma_f32_16x16x32_bf16(vf, pfrag, z, 0, 0, 0);
    }
    #pragma unroll
    for (int ct = 0; ct < 4; ++ct){
      uint2v ow;
      ow.x = pack2bf(dd[ct][0] * inv, dd[ct][1] * inv);
      ow.y = pack2bf(dd[ct][2] * inv, dd[ct][3] * inv);
      *(uint2v*)(osh + r * 72 + ct * 16 + 4 * g) = ow;
    }
    int frow = lane >> 2, fch = lane & 3;
    ushort8v t0 = *(const ushort8v*)(osh + frow * 72 + fch * 16);
    ushort8v t1 = *(const ushort8v*)(osh + frow * 72 + fch * 16 + 8);
    unsigned short* gdst = qraw + ((size_t)(b * HW_ + row0 + frow) * 512) + h * 64 + fch * 16;
    *(ushort8v*)(gdst)     = t0;
    *(ushort8v*)(gdst + 8) = t1;
  }
}

// --------------------------- h = gelu(vis) * IN(yw) (in-place over yw) ------
__global__ __launch_bounds__(256) void k_hmul(unsigned short* __restrict__ yw,
    const unsigned short* __restrict__ visb, const float2* __restrict__ stats)
{
  const int b = blockIdx.y, blk = blockIdx.x;
  const int w = threadIdx.x >> 6, lane = threadIdx.x & 63;
  const int c0 = lane * 8;
  float mean[8], inv[8];
  #pragma unroll
  for (int j = 0; j < 8; ++j){
    float2 st = stats[(size_t)b * 512 + c0 + j];
    mean[j] = st.x; inv[j] = st.y;
  }
  for (int it = 0; it < 30; ++it){
    int row = blk * 120 + it * 4 + w;
    size_t off = ((size_t)b * HW_ + row) * 512 + c0;
    ushort8v yv = *(const ushort8v*)(yw + off);
    ushort8v vv = *(const ushort8v*)(visb + off);
    ushort8v hv;
    #pragma unroll
    for (int j = 0; j < 8; ++j){
      float lang = (bf2f(yv[j]) - mean[j]) * inv[j];
      float visg = gelu_f(bf2f(vv[j]));
      hv[j] = f2bf(visg * lang);
    }
    *(ushort8v*)(yw + off) = hv;
  }
}

// ---------------------------------------------------------------------------
extern "C" void kernel_launch(void* const* d_in, const int* in_sizes, int n_in,
                              void* d_out, int out_size, void* d_ws, size_t ws_size,
                              hipStream_t stream)
{
  const float* x     = (const float*)d_in[0];
  const float* l     = (const float*)d_in[1];
  const float* lmask = (const float*)d_in[2];
  const float* Wvis  = (const float*)d_in[3];
  const float* bvis  = (const float*)d_in[4];
  const float* Wq    = (const float*)d_in[5];
  const float* bq    = (const float*)d_in[6];
  const float* Wk    = (const float*)d_in[7];
  const float* bk    = (const float*)d_in[8];
  const float* Wval  = (const float*)d_in[9];
  const float* bval  = (const float*)d_in[10];
  const float* Ww    = (const float*)d_in[11];
  const float* bw    = (const float*)d_in[12];
  const float* Wmm   = (const float*)d_in[13];
  const float* bmm   = (const float*)d_in[14];
  float* out = (float*)d_out;

  char* ws = (char*)d_ws;
  if (ws_size < 240517120ull) return;
  unsigned short* visb  = (unsigned short*)(ws + 58982400);
  unsigned short* qraw  = (unsigned short*)(ws + 117964800);
  unsigned short* yw    = (unsigned short*)(ws + 176947200);
  unsigned short* wcat  = (unsigned short*)(ws + 235929600);
  unsigned short* wwb   = (unsigned short*)(ws + 236978176);
  unsigned short* wmmb  = (unsigned short*)(ws + 237502464);
  float*  k_s    = (float*)(ws + 238026752);
  float*  v_s    = (float*)(ws + 238682112);
  float2* stats_w= (float2*)(ws + 240451584);
  unsigned short* k2 = (unsigned short*)(ws + 0);          // 512 KB (old xb region)
  unsigned short* v2 = (unsigned short*)(ws + 524288);     // 512 KB
  float*          e_s = (float*)(ws + 1048576);            // 2 KB
  float2* partial_q = (float2*)(ws + 176947200);           // yw region (dead during gemm0)
  float2* partial_w = (float2*)(ws + 1052672);             // old-xb region (dead during gemm1)

  // 1) weight conversions only (x is converted inside gemm0)
  k_cvt_w<<<512, 256, 0, stream>>>(Wvis, Wq, Ww, Wmm, wcat, wwb, wmmb);

  // 2) K/V projections (mask + bias + 1/sqrt(KC) folded)
  k_kv<<<dim3(16, B_), 256, 0, stream>>>(l, lmask, Wk, bk, Wval, bval, k_s, v_s);

  // 3) dual GEMM from f32 x: visb = x@Wvis^T+bvis (RAW), qraw = x@Wq^T+bq (+ q-stats)
  k_gemm<0, 8, true, true><<<29 * 8 * B_, 256, 0, stream>>>(nullptr, x, wcat, bvis, bq, visb, qraw, nullptr, partial_q);

  // 4) prep: q-stats finalize (in LDS) + MFMA fragments + e_s
  k_prep<<<B_, 256, 0, stream>>>(partial_q, k_s, v_s, lmask, k2, v2, e_s);

  // 5) MFMA attention, in-place over qraw
  k_attn2<<<dim3(57, B_), 256, 0, stream>>>(qraw, k2, v2, e_s);

  // 6) yw = attn_out @ Ww^T + bw  (+ w-stats partials)
  k_gemm<1, 4, true, false><<<29 * 4 * B_, 256, 0, stream>>>(qraw, x, wwb, bw, nullptr, yw, nullptr, nullptr, partial_w);

  // 7) IN stats for yw (stage 2)
  k_stats_p2b<<<B_, 512, 0, stream>>>(partial_w, stats_w);

  // 8) h = gelu(vis) * IN(yw)   (in-place over yw)
  k_hmul<<<dim3(30, B_), 256, 0, stream>>>(yw, visb, stats_w);

  // 9) out = gelu(h @ Wmm^T + bmm)  (f32)
  k_gemm<2, 4, false, false><<<29 * 4 * B_, 256, 0, stream>>>(yw, x, wmmb, bmm, nullptr, nullptr, nullptr, out, nullptr);
}

// Round 16
// 348.678 us; speedup vs baseline: 2.3606x; 1.0853x over previous
//
#include <hip/hip_runtime.h>

// ---------------------------------------------------------------------------
// PWAM fused pipeline, bf16 MFMA GEMMs + MFMA attention (swapped-QK, IN folded)
// R16: R15 with the epilogue staging stride reverted 68 -> 64 (stride-68
//      overflowed the 4096-short wave region: 64 rows x 68 = 4347 > 4096,
//      cross-wave LDS corruption). Everything else is the R12-proven set:
//      merged cvt, gload_lds staging, 32KB LDS, per-wr stats partials,
//      launch_bounds(256,4).
// B=16, HW=3600, D=KC=VC=512, LC=768, NL=20, H=8
// ---------------------------------------------------------------------------

#define B_   16
#define HW_  3600
#define D_   512
#define LC_  768
#define NL_  20

typedef __attribute__((ext_vector_type(8))) __bf16 bf16x8;
typedef __attribute__((ext_vector_type(4))) float f32x4;
typedef __attribute__((ext_vector_type(4))) float float4v;
typedef __attribute__((ext_vector_type(8))) unsigned short ushort8v;
typedef __attribute__((ext_vector_type(4))) unsigned short ushort4v;
typedef __attribute__((ext_vector_type(2))) unsigned int uint2v;

static __device__ __forceinline__ float bf2f(unsigned short u){
  unsigned int x = ((unsigned int)u) << 16; float f;
  __builtin_memcpy(&f, &x, 4); return f;
}
static __device__ __forceinline__ unsigned short f2bf(float f){
  __bf16 h = (__bf16)f;
  unsigned short u; __builtin_memcpy(&u, &h, 2); return u;
}
static __device__ __forceinline__ unsigned int pack2bf(float lo, float hi){
  return (unsigned int)f2bf(lo) | ((unsigned int)f2bf(hi) << 16);
}
// gelu(x) = 0.5x(1+erf(x/sqrt2)); erf via A&S 7.1.26 (|err|<=1.5e-7), hw exp.
static __device__ __forceinline__ float gelu_f(float x){
  float z  = x * 0.7071067811865476f;
  float az = fabsf(z);
  float t = 1.0f / fmaf(0.3275911f, az, 1.0f);
  float p = fmaf(1.061405429f, t, -1.453152027f);
  p = fmaf(p, t, 1.421413741f);
  p = fmaf(p, t, -0.284496736f);
  p = fmaf(p, t, 0.254829592f);
  p = p * t;
  float er = 1.0f - p * __expf(-az * az);
  er = copysignf(er, z);
  return 0.5f * x * (1.0f + er);
}

// --------------------------- merged f32 -> bf16 convert ---------------------
__global__ void k_cvt_all(const float* __restrict__ x,
                          const float* __restrict__ Wvis, const float* __restrict__ Wq,
                          const float* __restrict__ Ww,   const float* __restrict__ Wmm,
                          unsigned short* __restrict__ xb, unsigned short* __restrict__ wcat,
                          unsigned short* __restrict__ wwb, unsigned short* __restrict__ wmmb){
  const int NX4 = (B_ * HW_ * D_) / 4;         // 7,372,800
  const int TOT = NX4 + 4 * 65536;
  int i = blockIdx.x * 256 + threadIdx.x;
  int stride = gridDim.x * 256;
  for (; i < TOT; i += stride){
    const float4v* s; ushort4v* dp;
    if (i < NX4){
      s  = (const float4v*)x + i;
      dp = (ushort4v*)xb + i;
    } else {
      int k = i - NX4;
      int seg = k >> 16, o = k & 0xFFFF;
      if      (seg == 0){ s = (const float4v*)Wvis + o; dp = (ushort4v*)wcat + o; }
      else if (seg == 1){ s = (const float4v*)Wq   + o; dp = (ushort4v*)wcat + 65536 + o; }
      else if (seg == 2){ s = (const float4v*)Ww   + o; dp = (ushort4v*)wwb + o; }
      else              { s = (const float4v*)Wmm  + o; dp = (ushort4v*)wmmb + o; }
    }
    float4v v = *s;
    ushort4v u;
    u.x = f2bf(v.x); u.y = f2bf(v.y); u.z = f2bf(v.z); u.w = f2bf(v.w);
    *dp = u;
  }
}

// --------------------------- K/V projections (tiny) -------------------------
__global__ void k_kv(const float* __restrict__ l, const float* __restrict__ l_mask,
                     const float* __restrict__ Wk, const float* __restrict__ bk,
                     const float* __restrict__ Wval, const float* __restrict__ bval,
                     float* __restrict__ k_s, float* __restrict__ v_s){
  const int b = blockIdx.y;
  const int part = blockIdx.x;
  const bool isK = part < 8;
  const int c0 = (part & 7) * 64;
  const float* W  = isK ? Wk : Wval;
  const float* bi = isK ? bk : bval;
  float* outp = isK ? k_s : v_s;

  __shared__ float l_sh[LC_ * NL_];
  for (int i = threadIdx.x; i < LC_ * NL_; i += 256)
    l_sh[i] = l[(size_t)b * LC_ * NL_ + i];
  __syncthreads();

  const int tid = threadIdx.x;
  const int cl = tid >> 2;
  const int q  = tid & 3;
  const int c  = c0 + cl;
  const float* wrow = W + (size_t)c * LC_;
  float acc[5] = {0.f,0.f,0.f,0.f,0.f};
  for (int i = 0; i < LC_; ++i){
    float wv = wrow[i];
    const float* lr = l_sh + i * NL_ + q * 5;
    acc[0] = fmaf(wv, lr[0], acc[0]);
    acc[1] = fmaf(wv, lr[1], acc[1]);
    acc[2] = fmaf(wv, lr[2], acc[2]);
    acc[3] = fmaf(wv, lr[3], acc[3]);
    acc[4] = fmaf(wv, lr[4], acc[4]);
  }
  const float bb = bi[c];
  #pragma unroll
  for (int n5 = 0; n5 < 5; ++n5){
    int n = q * 5 + n5;
    float m = l_mask[b * NL_ + n];
    float val = (acc[n5] + bb) * m;
    if (isK) val *= 0.04419417382415922f;   // 1/sqrt(512) folded into K
    outp[((size_t)b * 512 + c) * NL_ + n] = val;
  }
}

// --------------------------- GEMM (bf16 MFMA, 128x128 tile) -----------------
// 2-buffer LDS = exactly 32KB, 4 blocks/CU. R6 sync discipline. XOR bank
// swizzle both sides. Vectorized LDS-staged epilogue (stride 64, exact fit).
// MODE 0: dual out (NT=8): n<512 -> o0=bf16(v) RAW (gelu in hmul); else o1=bf16(v)
// MODE 1: o0 = bf16(v);  MODE 2: of = gelu(v) f32
template<int MODE, int NT, bool STATS>
__global__ __launch_bounds__(256, 4) void k_gemm(
    const unsigned short* __restrict__ A,
    const unsigned short* __restrict__ Bm,
    const float* __restrict__ bias0, const float* __restrict__ bias1,
    unsigned short* __restrict__ o0, unsigned short* __restrict__ o1,
    float* __restrict__ of, float2* __restrict__ partial)
{
  __shared__ __align__(16) unsigned short smem[2][2][128 * 32];  // exactly 32 KB

  const int nwg = 29 * NT * B_;
  const int per = nwg >> 3;
  const int d = blockIdx.x;
  const int g = (d & 7) * per + (d >> 3);
  constexpr int NSH = (NT == 8) ? 3 : 2;
  const int nt = g & (NT - 1);
  const int rem = g >> NSH;
  const int mt = rem % 29;
  const int b  = rem / 29;

  const int m0 = mt * 128;
  const int n0 = nt * 128;
  const int tid = threadIdx.x;
  const int w = tid >> 6, lane = tid & 63;
  const int wr = w >> 1, wc = w & 1;
  const int lr_ = lane & 15, lg_ = lane >> 4;
  const int mvalid = HW_ - m0;
  const unsigned short* Ab = A + (size_t)b * HW_ * 512;

  f32x4 acc[4][4];
  #pragma unroll
  for (int i = 0; i < 4; ++i)
    #pragma unroll
    for (int j = 0; j < 4; ++j)
      acc[i][j] = (f32x4){0.f, 0.f, 0.f, 0.f};

  auto stage = [&](int kt, int buf){
    const int k0 = kt * 32;
    #pragma unroll
    for (int s = 0; s < 2; ++s){
      int chunk = s * 256 + tid;
      int row = chunk >> 2, part = chunk & 3;
      int psrc = part ^ ((row >> 1) & 3);
      int grow = row < mvalid ? row : (mvalid - 1);
      const unsigned short* gsrc = Ab + ((size_t)(m0 + grow) * 512 + k0 + psrc * 8);
      unsigned short* ldst = &smem[0][buf][(s * 256 + w * 64) * 8];
      __builtin_amdgcn_global_load_lds((const __attribute__((address_space(1))) void*)gsrc,
                                       (__attribute__((address_space(3))) void*)ldst, 16, 0, 0);
    }
    #pragma unroll
    for (int s = 0; s < 2; ++s){
      int chunk = s * 256 + tid;
      int row = chunk >> 2, part = chunk & 3;
      int psrc = part ^ ((row >> 1) & 3);
      const unsigned short* gsrc = Bm + ((size_t)(n0 + row) * 512 + k0 + psrc * 8);
      unsigned short* ldst = &smem[1][buf][(s * 256 + w * 64) * 8];
      __builtin_amdgcn_global_load_lds((const __attribute__((address_space(1))) void*)gsrc,
                                       (__attribute__((address_space(3))) void*)ldst, 16, 0, 0);
    }
  };

  auto compute = [&](int buf){
    const unsigned short* lA = &smem[0][buf][(wr * 64) * 32];
    const unsigned short* lB = &smem[1][buf][(wc * 64) * 32];
    const int kx = (lg_ ^ ((lr_ >> 1) & 3)) * 8;   // swizzled 16B slot
    bf16x8 av[4], bv[4];
    #pragma unroll
    for (int i = 0; i < 4; ++i) av[i] = *(const bf16x8*)(lA + (i * 16 + lr_) * 32 + kx);
    #pragma unroll
    for (int j = 0; j < 4; ++j) bv[j] = *(const bf16x8*)(lB + (j * 16 + lr_) * 32 + kx);
    #pragma unroll
    for (int i = 0; i < 4; ++i)
      #pragma unroll
      for (int j = 0; j < 4; ++j)
        acc[i][j] = __builtin_amdgcn_mfma_f32_16x16x32_bf16(av[i], bv[j], acc[i][j], 0, 0, 0);
  };

  stage(0, 0);
  #pragma unroll
  for (int t = 0; t < 16; ++t){
    asm volatile("s_waitcnt lgkmcnt(0)" ::: "memory");
    __builtin_amdgcn_sched_barrier(0);
    asm volatile("s_waitcnt vmcnt(0)" ::: "memory");
    __builtin_amdgcn_s_barrier();
    __builtin_amdgcn_sched_barrier(0);
    if (t < 15) stage(t + 1, (t + 1) & 1);
    compute(t & 1);
  }

  // ---- epilogue ----
  const int colbase = n0 + wc * 64;
  float bsv[4];
  #pragma unroll
  for (int j = 0; j < 4; ++j){
    int col = colbase + j * 16 + lr_;
    if (MODE == 0) bsv[j] = (col < 512) ? bias0[col] : bias1[col - 512];
    else           bsv[j] = bias0[col];
  }
  const bool do_stats = STATS && (MODE != 0 || n0 >= 512);

  if (STATS && do_stats){
    float colsum[4] = {0.f,0.f,0.f,0.f}, colsq[4] = {0.f,0.f,0.f,0.f};
    #pragma unroll
    for (int i = 0; i < 4; ++i){
      int rowb = m0 + wr * 64 + i * 16 + lg_ * 4;
      #pragma unroll
      for (int rr = 0; rr < 4; ++rr){
        if (rowb + rr < HW_){
          #pragma unroll
          for (int j = 0; j < 4; ++j){
            float v = acc[i][j][rr] + bsv[j];
            colsum[j] += v;
            colsq[j]  = fmaf(v, v, colsq[j]);
          }
        }
      }
    }
    #pragma unroll
    for (int j = 0; j < 4; ++j){
      colsum[j] += __shfl_xor(colsum[j], 16);
      colsum[j] += __shfl_xor(colsum[j], 32);
      colsq[j]  += __shfl_xor(colsq[j], 16);
      colsq[j]  += __shfl_xor(colsq[j], 32);
    }
    if (lg_ == 0){
      #pragma unroll
      for (int j = 0; j < 4; ++j){
        int gcol = colbase + j * 16 + lr_ - (MODE == 0 ? 512 : 0);
        partial[((size_t)b * 29 + mt) * 1024 + wr * 512 + gcol] =
          make_float2(colsum[j], colsq[j]);
      }
    }
  }

  __syncthreads();   // K-loop LDS reads done -> smem reusable for C staging

  unsigned short* stw = &smem[0][0][0] + w * 4096;   // 8KB wave-private region

  if (MODE == 2){
    float* stgf = (float*)stw;   // [32][64] f32 per half-pass (8KB exact)
    #pragma unroll
    for (int half = 0; half < 2; ++half){
      #pragma unroll
      for (int i2 = 0; i2 < 2; ++i2){
        int i = half * 2 + i2;
        #pragma unroll
        for (int rr = 0; rr < 4; ++rr)
          #pragma unroll
          for (int j = 0; j < 4; ++j)
            stgf[(i2 * 16 + lg_ * 4 + rr) * 64 + j * 16 + lr_] = gelu_f(acc[i][j][rr] + bsv[j]);
      }
      #pragma unroll
      for (int pass = 0; pass < 8; ++pass){
        int chunk = pass * 64 + lane;
        int row = chunk >> 4, sub = chunk & 15;
        float4v vv = *(const float4v*)(stgf + row * 64 + sub * 4);
        int grow = m0 + wr * 64 + half * 32 + row;
        if (grow < HW_)
          *(float4v*)(of + ((size_t)b * HW_ + grow) * 512 + colbase + sub * 4) = vv;
      }
    }
  } else {
    // [64][64] bf16 = 4096 shorts, exact fit in the 8KB wave region.
    #pragma unroll
    for (int i = 0; i < 4; ++i)
      #pragma unroll
      for (int rr = 0; rr < 4; ++rr)
        #pragma unroll
        for (int j = 0; j < 4; ++j){
          float v = acc[i][j][rr] + bsv[j];
          stw[(i * 16 + lg_ * 4 + rr) * 64 + j * 16 + lr_] = f2bf(v);
        }
    unsigned short* optr = (MODE == 1 || n0 < 512) ? o0 : o1;
    const int coloff = (MODE == 1 || n0 < 512) ? colbase : (colbase - 512);
    #pragma unroll
    for (int pass = 0; pass < 8; ++pass){
      int chunk = pass * 64 + lane;
      int row = chunk >> 3, sub = chunk & 7;
      ushort8v vv = *(const ushort8v*)(stw + row * 64 + sub * 8);
      int grow = m0 + wr * 64 + row;
      if (grow < HW_)
        *(ushort8v*)(optr + ((size_t)b * HW_ + grow) * 512 + coloff + sub * 8) = vv;
    }
  }
}

// --------------------------- IN stats stage-2 (w; 29x2 partials) ------------
__global__ void k_stats_p2b(const float2* __restrict__ partial, float2* __restrict__ stats){
  const int b = blockIdx.x;
  const int c = threadIdx.x;   // 512
  float s = 0.f, q = 0.f;
  for (int mt = 0; mt < 29; ++mt){
    float2 p0 = partial[((size_t)b * 29 + mt) * 1024 + c];
    float2 p1 = partial[((size_t)b * 29 + mt) * 1024 + 512 + c];
    s += p0.x + p1.x; q += p0.y + p1.y;
  }
  float mean = s * (1.0f / (float)HW_);
  float var  = q * (1.0f / (float)HW_) - mean * mean;
  stats[(size_t)b * 512 + c] = make_float2(mean, rsqrtf(var + 1e-5f));
}

// --------------------------- attention prep (+fused q-stats) ----------------
__global__ void k_prep(const float2* __restrict__ partial, const float* __restrict__ k_s,
                       const float* __restrict__ v_s, const float* __restrict__ l_mask,
                       unsigned short* __restrict__ k2, unsigned short* __restrict__ v2,
                       float* __restrict__ e_s)
{
  const int b = blockIdx.x;
  const int tid = threadIdx.x;
  __shared__ float wred[4][NL_];
  __shared__ float2 stats_sh[512];

  #pragma unroll
  for (int half = 0; half < 2; ++half){
    int c = tid + half * 256;
    float s = 0.f, q = 0.f;
    for (int mt = 0; mt < 29; ++mt){
      float2 p0 = partial[((size_t)b * 29 + mt) * 1024 + c];
      float2 p1 = partial[((size_t)b * 29 + mt) * 1024 + 512 + c];
      s += p0.x + p1.x; q += p0.y + p1.y;
    }
    float mean = s * (1.0f / (float)HW_);
    float var  = q * (1.0f / (float)HW_) - mean * mean;
    stats_sh[c] = make_float2(mean, rsqrtf(var + 1e-5f));
  }
  __syncthreads();

  float part[NL_];
  #pragma unroll
  for (int n = 0; n < NL_; ++n) part[n] = 0.f;
  #pragma unroll
  for (int half = 0; half < 2; ++half){
    int c = tid + half * 256;
    float2 st = stats_sh[c];
    float ms = st.x * st.y;
    const float* row = k_s + ((size_t)b * 512 + c) * NL_;
    #pragma unroll
    for (int n = 0; n < NL_; ++n) part[n] = fmaf(ms, row[n], part[n]);
  }
  #pragma unroll
  for (int n = 0; n < NL_; ++n){
    float v = part[n];
    v += __shfl_xor(v, 1);  v += __shfl_xor(v, 2);  v += __shfl_xor(v, 4);
    v += __shfl_xor(v, 8);  v += __shfl_xor(v, 16); v += __shfl_xor(v, 32);
    part[n] = v;
  }
  if ((tid & 63) == 0){
    #pragma unroll
    for (int n = 0; n < NL_; ++n) wred[tid >> 6][n] = part[n];
  }
  __syncthreads();
  if (tid < 32){
    float e;
    if (tid < NL_){
      float dsum = wred[0][tid] + wred[1][tid] + wred[2][tid] + wred[3][tid];
      e = -dsum - 10000.0f * (1.0f - l_mask[b * NL_ + tid]);
    } else {
      e = -1e30f;
    }
    e_s[b * 32 + tid] = e;
  }

  for (int i = tid; i < 16384; i += 256){
    int h = i >> 11, t = (i >> 10) & 1, s = (i >> 9) & 1;
    int l = (i >> 3) & 63, j = i & 7;
    int r = l & 15, g = l >> 4;
    int n = t * 16 + r;
    int c = h * 64 + s * 32 + g * 8 + j;
    unsigned short val = 0;
    if (n < NL_){
      float inv = stats_sh[c].y;
      val = f2bf(inv * k_s[((size_t)b * 512 + c) * NL_ + n]);
    }
    k2[(size_t)b * 16384 + i] = val;
  }
  for (int i = tid; i < 16384; i += 256){
    int h = i >> 11, ct = (i >> 9) & 3;
    int l = (i >> 3) & 63, j = i & 7;
    int r = l & 15, g = l >> 4;
    int n = g * 8 + j;
    int c = h * 64 + ct * 16 + r;
    unsigned short val = 0;
    if (n < NL_) val = f2bf(v_s[((size_t)b * 512 + c) * NL_ + n]);
    v2[(size_t)b * 16384 + i] = val;
  }
}

// --------------------------- attention (MFMA, swapped-QK) -------------------
__global__ __launch_bounds__(256) void k_attn2(unsigned short* __restrict__ qraw,
    const unsigned short* __restrict__ k2, const unsigned short* __restrict__ v2,
    const float* __restrict__ e_s)
{
  const int b = blockIdx.y;
  const int w = threadIdx.x >> 6;
  const int tile = blockIdx.x * 4 + w;
  __shared__ __align__(16) unsigned short p_sh[4][16 * 32];
  __shared__ __align__(16) unsigned short o_sh[4][16 * 72];
  if (tile >= 225) return;
  const int lane = threadIdx.x & 63;
  const int r = lane & 15, g = lane >> 4;
  const int row0 = tile * 16;

  float4v e0 = *(const float4v*)(e_s + b * 32 + g * 4);
  float4v e1 = *(const float4v*)(e_s + b * 32 + 16 + g * 4);

  bf16x8 qf[8][2];
  const unsigned short* qbase = qraw + ((size_t)(b * HW_ + row0 + r) * 512) + g * 8;
  #pragma unroll
  for (int h = 0; h < 8; ++h)
    #pragma unroll
    for (int s = 0; s < 2; ++s)
      qf[h][s] = *(const bf16x8*)(qbase + h * 64 + s * 32);

  const unsigned short* kb = k2 + (size_t)b * 16384 + lane * 8;
  const unsigned short* vb = v2 + (size_t)b * 16384 + lane * 8;
  unsigned short* psh = &p_sh[w][0];
  unsigned short* osh = &o_sh[w][0];

  for (int h = 0; h < 8; ++h){
    bf16x8 kf00 = *(const bf16x8*)(kb + (h * 4 + 0) * 512);
    bf16x8 kf01 = *(const bf16x8*)(kb + (h * 4 + 1) * 512);
    bf16x8 kf10 = *(const bf16x8*)(kb + (h * 4 + 2) * 512);
    bf16x8 kf11 = *(const bf16x8*)(kb + (h * 4 + 3) * 512);
    f32x4 c0 = (f32x4){0.f,0.f,0.f,0.f};
    f32x4 c1 = (f32x4){0.f,0.f,0.f,0.f};
    c0 = __builtin_amdgcn_mfma_f32_16x16x32_bf16(kf00, qf[h][0], c0, 0, 0, 0);
    c0 = __builtin_amdgcn_mfma_f32_16x16x32_bf16(kf01, qf[h][1], c0, 0, 0, 0);
    c1 = __builtin_amdgcn_mfma_f32_16x16x32_bf16(kf10, qf[h][0], c1, 0, 0, 0);
    c1 = __builtin_amdgcn_mfma_f32_16x16x32_bf16(kf11, qf[h][1], c1, 0, 0, 0);

    float l0[4], l1[4];
    #pragma unroll
    for (int i = 0; i < 4; ++i){ l0[i] = c0[i] + e0[i]; l1[i] = c1[i] + e1[i]; }
    float m = fmaxf(fmaxf(fmaxf(l0[0], l0[1]), fmaxf(l0[2], l0[3])),
                    fmaxf(fmaxf(l1[0], l1[1]), fmaxf(l1[2], l1[3])));
    m = fmaxf(m, __shfl_xor(m, 16));
    m = fmaxf(m, __shfl_xor(m, 32));
    float p0[4], p1[4];
    #pragma unroll
    for (int i = 0; i < 4; ++i){ p0[i] = __expf(l0[i] - m); p1[i] = __expf(l1[i] - m); }

    uint2v pw0, pw1;
    pw0.x = pack2bf(p0[0], p0[1]); pw0.y = pack2bf(p0[2], p0[3]);
    pw1.x = pack2bf(p1[0], p1[1]); pw1.y = pack2bf(p1[2], p1[3]);
    float sum = bf2f((unsigned short)(pw0.x & 0xffff)) + bf2f((unsigned short)(pw0.x >> 16))
              + bf2f((unsigned short)(pw0.y & 0xffff)) + bf2f((unsigned short)(pw0.y >> 16))
              + bf2f((unsigned short)(pw1.x & 0xffff)) + bf2f((unsigned short)(pw1.x >> 16))
              + bf2f((unsigned short)(pw1.y & 0xffff)) + bf2f((unsigned short)(pw1.y >> 16));
    sum += __shfl_xor(sum, 16);
    sum += __shfl_xor(sum, 32);
    float inv = 1.0f / sum;

    *(uint2v*)(psh + r * 32 + 4 * g)      = pw0;
    *(uint2v*)(psh + r * 32 + 16 + 4 * g) = pw1;
    bf16x8 pfrag = *(const bf16x8*)(psh + r * 32 + g * 8);

    f32x4 dd[4];
    #pragma unroll
    for (int ct = 0; ct < 4; ++ct){
      bf16x8 vf = *(const bf16x8*)(vb + (h * 4 + ct) * 512);
      f32x4 z = (f32x4){0.f,0.f,0.f,0.f};
      dd[ct] = __builtin_amdgcn_mfma_f32_16x16x32_bf16(vf, pfrag, z, 0, 0, 0);
    }
    #pragma unroll
    for (int ct = 0; ct < 4; ++ct){
      uint2v ow;
      ow.x = pack2bf(dd[ct][0] * inv, dd[ct][1] * inv);
      ow.y = pack2bf(dd[ct][2] * inv, dd[ct][3] * inv);
      *(uint2v*)(osh + r * 72 + ct * 16 + 4 * g) = ow;
    }
    int frow = lane >> 2, fch = lane & 3;
    ushort8v t0 = *(const ushort8v*)(osh + frow * 72 + fch * 16);
    ushort8v t1 = *(const ushort8v*)(osh + frow * 72 + fch * 16 + 8);
    unsigned short* gdst = qraw + ((size_t)(b * HW_ + row0 + frow) * 512) + h * 64 + fch * 16;
    *(ushort8v*)(gdst)     = t0;
    *(ushort8v*)(gdst + 8) = t1;
  }
}

// --------------------------- h = gelu(vis) * IN(yw) (in-place over yw) ------
__global__ __launch_bounds__(256) void k_hmul(unsigned short* __restrict__ yw,
    const unsigned short* __restrict__ visb, const float2* __restrict__ stats)
{
  const int b = blockIdx.y, blk = blockIdx.x;
  const int w = threadIdx.x >> 6, lane = threadIdx.x & 63;
  const int c0 = lane * 8;
  float mean[8], inv[8];
  #pragma unroll
  for (int j = 0; j < 8; ++j){
    float2 st = stats[(size_t)b * 512 + c0 + j];
    mean[j] = st.x; inv[j] = st.y;
  }
  for (int it = 0; it < 30; ++it){
    int row = blk * 120 + it * 4 + w;
    size_t off = ((size_t)b * HW_ + row) * 512 + c0;
    ushort8v yv = *(const ushort8v*)(yw + off);
    ushort8v vv = *(const ushort8v*)(visb + off);
    ushort8v hv;
    #pragma unroll
    for (int j = 0; j < 8; ++j){
      float lang = (bf2f(yv[j]) - mean[j]) * inv[j];
      float visg = gelu_f(bf2f(vv[j]));
      hv[j] = f2bf(visg * lang);
    }
    *(ushort8v*)(yw + off) = hv;
  }
}

// ---------------------------------------------------------------------------
extern "C" void kernel_launch(void* const* d_in, const int* in_sizes, int n_in,
                              void* d_out, int out_size, void* d_ws, size_t ws_size,
                              hipStream_t stream)
{
  const float* x     = (const float*)d_in[0];
  const float* l     = (const float*)d_in[1];
  const float* lmask = (const float*)d_in[2];
  const float* Wvis  = (const float*)d_in[3];
  const float* bvis  = (const float*)d_in[4];
  const float* Wq    = (const float*)d_in[5];
  const float* bq    = (const float*)d_in[6];
  const float* Wk    = (const float*)d_in[7];
  const float* bk    = (const float*)d_in[8];
  const float* Wval  = (const float*)d_in[9];
  const float* bval  = (const float*)d_in[10];
  const float* Ww    = (const float*)d_in[11];
  const float* bw    = (const float*)d_in[12];
  const float* Wmm   = (const float*)d_in[13];
  const float* bmm   = (const float*)d_in[14];
  float* out = (float*)d_out;

  char* ws = (char*)d_ws;
  if (ws_size < 240517120ull) return;
  unsigned short* xb    = (unsigned short*)(ws + 0);
  unsigned short* visb  = (unsigned short*)(ws + 58982400);
  unsigned short* qraw  = (unsigned short*)(ws + 117964800);
  unsigned short* yw    = (unsigned short*)(ws + 176947200);
  unsigned short* wcat  = (unsigned short*)(ws + 235929600);
  unsigned short* wwb   = (unsigned short*)(ws + 236978176);
  unsigned short* wmmb  = (unsigned short*)(ws + 237502464);
  float*  k_s    = (float*)(ws + 238026752);
  float*  v_s    = (float*)(ws + 238682112);
  float2* stats_w= (float2*)(ws + 240451584);
  unsigned short* k2 = (unsigned short*)(ws + 0);          // 512 KB (dead xb after gemm0)
  unsigned short* v2 = (unsigned short*)(ws + 524288);     // 512 KB
  float*          e_s = (float*)(ws + 1048576);            // 2 KB
  float2* partial_q = (float2*)(ws + 176947200);           // yw region (dead during gemm0)
  float2* partial_w = (float2*)(ws + 1052672);             // xb region (dead during gemm1)

  // 1) bf16 conversions (x + weights, one launch)
  k_cvt_all<<<2048, 256, 0, stream>>>(x, Wvis, Wq, Ww, Wmm, xb, wcat, wwb, wmmb);

  // 2) K/V projections (mask + bias + 1/sqrt(KC) folded)
  k_kv<<<dim3(16, B_), 256, 0, stream>>>(l, lmask, Wk, bk, Wval, bval, k_s, v_s);

  // 3) dual GEMM: visb = x@Wvis^T+bvis (RAW), qraw = x@Wq^T+bq  (+ q-stats partials)
  k_gemm<0, 8, true><<<29 * 8 * B_, 256, 0, stream>>>(xb, wcat, bvis, bq, visb, qraw, nullptr, partial_q);

  // 4) prep: q-stats finalize (in LDS) + MFMA fragments + e_s
  k_prep<<<B_, 256, 0, stream>>>(partial_q, k_s, v_s, lmask, k2, v2, e_s);

  // 5) MFMA attention, in-place over qraw
  k_attn2<<<dim3(57, B_), 256, 0, stream>>>(qraw, k2, v2, e_s);

  // 6) yw = attn_out @ Ww^T + bw  (+ w-stats partials)
  k_gemm<1, 4, true><<<29 * 4 * B_, 256, 0, stream>>>(qraw, wwb, bw, nullptr, yw, nullptr, nullptr, partial_w);

  // 7) IN stats for yw (stage 2)
  k_stats_p2b<<<B_, 512, 0, stream>>>(partial_w, stats_w);

  // 8) h = gelu(vis) * IN(yw)   (in-place over yw)
  k_hmul<<<dim3(30, B_), 256, 0, stream>>>(yw, visb, stats_w);

  // 9) out = gelu(h @ Wmm^T + bmm)  (f32)
  k_gemm<2, 4, false><<<29 * 4 * B_, 256, 0, stream>>>(yw, wmmb, bmm, nullptr, nullptr, nullptr, out, nullptr);
}